// Round 5
// baseline (712.724 us; speedup 1.0000x reference)
//
#include <hip/hip_runtime.h>
#include <hip/hip_bf16.h>
#include <stdint.h>

// MHA forward, MI355X/gfx950.
// Pipeline: 3x projection GEMM (f32 in -> bf16 out) -> flash attention (bf16)
//           -> output GEMM (bf16 in -> f32 out + bias).
// All matmul via v_mfma_f32_16x16x32_bf16, fp32 accumulate.

typedef __bf16 bh;
typedef bh bh8 __attribute__((ext_vector_type(8)));
typedef float f4 __attribute__((ext_vector_type(4)));

#define DEVI static __device__ __forceinline__

constexpr int CB = 4, CS = 2048, CD = 1024, CH = 16;
constexpr int CM = CB * CS;  // 8192 rows

DEVI f4 mfma16(bh8 a, bh8 b, f4 c) {
  return __builtin_amdgcn_mfma_f32_16x16x32_bf16(a, b, c, 0, 0, 0);
}

// async global->LDS, 16B per lane. LDS dest is wave-uniform base + lane*16.
DEVI void gload_lds16(const void* g, void* l) {
  void* gnc = const_cast<void*>(g);
  __builtin_amdgcn_global_load_lds(
      (__attribute__((address_space(1))) void*)gnc,
      (__attribute__((address_space(3))) void*)l, 16, 0, 0);
}

// Read an 8-elem bf16 fragment from a [rows][64] XOR-swizzled LDS tile.
// Element (row,k) lives at byte (row*128 + k*2) ^ ((row&7)<<4).
DEVI bh8 frag_ld(const bh* base, int row, int k0) {
  int slot = (k0 >> 3) ^ (row & 7);
  return *(const bh8*)(base + row * 64 + slot * 8);
}

DEVI bh8 cvt8(float4 a, float4 b) {
  bh8 v;
  v[0] = (bh)a.x; v[1] = (bh)a.y; v[2] = (bh)a.z; v[3] = (bh)a.w;
  v[4] = (bh)b.x; v[5] = (bh)b.y; v[6] = (bh)b.z; v[7] = (bh)b.w;
  return v;
}

// Stage a 128x64 f32 tile -> swizzled bf16 LDS tile. 256 threads.
DEVI void stage_f32_tile(const float* src, int ld, bh* dst, int t) {
#pragma unroll
  for (int i = 0; i < 4; ++i) {
    int c2 = 2 * t + i * 512;        // float4-chunk index (16 per row), paired
    int row = c2 >> 4;
    int s8 = (c2 & 15) >> 1;         // 16B bf16 slot 0..7
    const float4* sp = (const float4*)(src + (size_t)row * ld) + (c2 & 15);
    float4 a = sp[0], b2 = sp[1];
    int slot = s8 ^ (row & 7);
    *(bh8*)(dst + row * 64 + slot * 8) = cvt8(a, b2);
  }
}

// Stage a 128x64 bf16 tile via global_load_lds: linear LDS dest,
// inverse-swizzled global source (rule #21).
DEVI void stage_bf16_tile(const bh* src, int ld, bh* dst, int wave, int lane) {
#pragma unroll
  for (int i = 0; i < 4; ++i) {
    int c = i * 256 + wave * 64 + lane;
    int row = c >> 3, s8 = c & 7;
    gload_lds16(src + (size_t)row * ld + ((s8 ^ (row & 7)) * 8), dst + c * 8);
  }
}

// C[M,N] = A[M,K] @ B[N,K]^T + bias.  128x128 tile, BK=64, 4 waves (2x2),
// each wave 64x64 out = 4x4 mfma subtiles.  1D grid, XCD-chunked swizzle.
template <bool A_F32, bool OUT_F32>
__global__ __launch_bounds__(256, 2) void gemm_bt(
    const void* __restrict__ Ap, const float* __restrict__ Bw,
    const float* __restrict__ bias, void* __restrict__ Cp,
    int M, int N, int K) {
  __shared__ __align__(16) bh Asm[128 * 64];
  __shared__ __align__(16) bh Bsm[128 * 64];
  const int t = threadIdx.x;
  const int lane = t & 63, wave = t >> 6;
  const int wm = wave >> 1, wn = wave & 1;

  // XCD-aware chunked swizzle (T1): nwg = ntx*nty, nwg%8==0 here (512).
  // HW round-robins blockIdx%8 across XCDs; give XCD c a contiguous 8x8
  // tile square so its A-panel working set fits L2.
  const int ntx = N >> 7, nty = M >> 7;
  const int c = blockIdx.x & 7;                  // XCD slot
  const int l = blockIdx.x >> 3;                 // index within chunk
  const int mt = c * (nty >> 3) + l / ntx;       // M-tile
  const int nt = l % ntx;                        // N-tile
  const int m0 = mt * 128, n0 = nt * 128;
  const int r15 = lane & 15, g4 = lane >> 4;

  const f4 fz = {0.f, 0.f, 0.f, 0.f};
  f4 acc[4][4];
#pragma unroll
  for (int i = 0; i < 4; ++i)
#pragma unroll
    for (int j = 0; j < 4; ++j) acc[i][j] = fz;

  for (int kt = 0; kt < K; kt += 64) {
    if constexpr (A_F32)
      stage_f32_tile((const float*)Ap + (size_t)m0 * K + kt, K, Asm, t);
    else
      stage_bf16_tile((const bh*)Ap + (size_t)m0 * K + kt, K, Asm, wave, lane);
    stage_f32_tile(Bw + (size_t)n0 * K + kt, K, Bsm, t);
    __syncthreads();

    bh8 af[4][2], bf_[4][2];
#pragma unroll
    for (int m = 0; m < 4; ++m)
#pragma unroll
      for (int kk = 0; kk < 2; ++kk)
        af[m][kk] = frag_ld(Asm, wm * 64 + m * 16 + r15, kk * 32 + g4 * 8);
#pragma unroll
    for (int n = 0; n < 4; ++n)
#pragma unroll
      for (int kk = 0; kk < 2; ++kk)
        bf_[n][kk] = frag_ld(Bsm, wn * 64 + n * 16 + r15, kk * 32 + g4 * 8);
#pragma unroll
    for (int kk = 0; kk < 2; ++kk)
#pragma unroll
      for (int m = 0; m < 4; ++m)
#pragma unroll
        for (int n = 0; n < 4; ++n)
          acc[m][n] = mfma16(af[m][kk], bf_[n][kk], acc[m][n]);
    __syncthreads();
  }

#pragma unroll
  for (int n = 0; n < 4; ++n) {
    int col = n0 + wn * 64 + n * 16 + r15;
    float bv = bias[col];
#pragma unroll
    for (int m = 0; m < 4; ++m) {
      int row = m0 + wm * 64 + m * 16 + g4 * 4;
#pragma unroll
      for (int r = 0; r < 4; ++r) {
        float v = acc[m][n][r] + bv;
        if constexpr (OUT_F32)
          ((float*)Cp)[(size_t)(row + r) * N + col] = v;
        else
          ((bh*)Cp)[(size_t)(row + r) * N + col] = (bh)v;
      }
    }
  }
}

// Flash attention, one (b,h) x 64 Q-rows per block; 4 waves, 16 rows/wave.
// K/V staged per 64-key tile; online softmax in registers via 16-lane shfl.
__global__ __launch_bounds__(256, 2) void attn_fwd(
    const bh* __restrict__ Qp, const bh* __restrict__ Kp,
    const bh* __restrict__ Vp, const int* __restrict__ maskp,
    bh* __restrict__ Op) {
  __shared__ __align__(16) bh Ksm[64 * 64];
  __shared__ __align__(16) bh Vtsm[64 * 64];   // V transposed: [d][k]
  __shared__ __align__(16) bh Psm[64 * 64];
  __shared__ float maskadd[64];

  const int t = threadIdx.x;
  const int lane = t & 63, wave = t >> 6;
  const int r15 = lane & 15, g4 = lane >> 4;
  const int b = blockIdx.y >> 4, h = blockIdx.y & 15;
  const int q0 = blockIdx.x * 64;

  const bh* Qb = Qp + ((size_t)(b * CS + q0)) * CD + h * 64;
  const bh* Kb = Kp + ((size_t)b * CS) * CD + h * 64;
  const bh* Vb = Vp + ((size_t)b * CS) * CD + h * 64;
  const int* mb = maskp + b * CS;

  // Q fragments in registers, pre-scaled by 1/sqrt(64)=0.125 (exact in bf16)
  bh8 qf[2];
  {
    int qr = wave * 16 + r15;
#pragma unroll
    for (int kk = 0; kk < 2; ++kk) {
      bh8 v = *(const bh8*)(Qb + (size_t)qr * CD + kk * 32 + g4 * 8);
#pragma unroll
      for (int j = 0; j < 8; ++j) v[j] = (bh)((float)v[j] * 0.125f);
      qf[kk] = v;
    }
  }

  const f4 fz = {0.f, 0.f, 0.f, 0.f};
  f4 acc_o[4];
#pragma unroll
  for (int i = 0; i < 4; ++i) acc_o[i] = fz;
  float mrow[4] = {-1e30f, -1e30f, -1e30f, -1e30f};
  float lrow[4] = {0.f, 0.f, 0.f, 0.f};

  for (int kt = 0; kt < CS; kt += 64) {
    // K tile via global_load_lds, pre-swizzled source
    const bh* Ks = Kb + (size_t)kt * CD;
#pragma unroll
    for (int i = 0; i < 2; ++i) {
      int c = i * 256 + wave * 64 + lane;
      int row = c >> 3, s8 = c & 7;
      gload_lds16(Ks + (size_t)row * CD + ((s8 ^ (row & 7)) * 8), Ksm + c * 8);
    }
    // V tile transposed into LDS (reg path, scalar writes)
    const bh* Vs = Vb + (size_t)kt * CD;
#pragma unroll
    for (int i = 0; i < 2; ++i) {
      int c = i * 256 + t;
      int k = c >> 3, d0 = (c & 7) * 8;
      bh8 v = *(const bh8*)(Vs + (size_t)k * CD + d0);
#pragma unroll
      for (int j = 0; j < 8; ++j) {
        int dr = d0 + j;
        Vtsm[dr * 64 + (((k >> 3) ^ (dr & 7)) << 3) + (k & 7)] = v[j];
      }
    }
    if (t < 64) maskadd[t] = (mb[kt + t] == 0) ? -1e9f : 0.0f;
    __syncthreads();

    // S = (Q/8) K^T ; acc layout: row=(g4*4+r) of wave strip, col=key tt*16+r15
    f4 s[4];
#pragma unroll
    for (int tt = 0; tt < 4; ++tt) {
      f4 a = fz;
#pragma unroll
      for (int kk = 0; kk < 2; ++kk) {
        bh8 kf = frag_ld(Ksm, tt * 16 + r15, kk * 32 + g4 * 8);
        a = mfma16(qf[kk], kf, a);
      }
      s[tt] = a;
    }

    // mask + online softmax (wave-parallel: 16-lane butterfly per row group)
    float madd[4];
#pragma unroll
    for (int tt = 0; tt < 4; ++tt) madd[tt] = maskadd[tt * 16 + r15];
    float mx[4];
#pragma unroll
    for (int r = 0; r < 4; ++r) {
      float v0 = s[0][r] + madd[0];
      s[0][r] = v0;
      mx[r] = v0;
    }
#pragma unroll
    for (int tt = 1; tt < 4; ++tt)
#pragma unroll
      for (int r = 0; r < 4; ++r) {
        float v = s[tt][r] + madd[tt];
        s[tt][r] = v;
        mx[r] = fmaxf(mx[r], v);
      }
#pragma unroll
    for (int off = 1; off < 16; off <<= 1)
#pragma unroll
      for (int r = 0; r < 4; ++r) mx[r] = fmaxf(mx[r], __shfl_xor(mx[r], off));

    float corr[4];
#pragma unroll
    for (int r = 0; r < 4; ++r) {
      float mn = fmaxf(mrow[r], mx[r]);
      corr[r] = __expf(mrow[r] - mn);
      mrow[r] = mn;
    }
    float psum[4];
#pragma unroll
    for (int tt = 0; tt < 4; ++tt)
#pragma unroll
      for (int r = 0; r < 4; ++r) {
        float p = __expf(s[tt][r] - mrow[r]);
        s[tt][r] = p;
        psum[r] = (tt == 0) ? p : (psum[r] + p);
      }
#pragma unroll
    for (int off = 1; off < 16; off <<= 1)
#pragma unroll
      for (int r = 0; r < 4; ++r) psum[r] += __shfl_xor(psum[r], off);
#pragma unroll
    for (int r = 0; r < 4; ++r) lrow[r] = lrow[r] * corr[r] + psum[r];
#pragma unroll
    for (int tt = 0; tt < 4; ++tt)
#pragma unroll
      for (int r = 0; r < 4; ++r) acc_o[tt][r] *= corr[r];

    // P -> LDS (bf16, swizzled). Wave-private rows: no barrier needed.
#pragma unroll
    for (int tt = 0; tt < 4; ++tt)
#pragma unroll
      for (int r = 0; r < 4; ++r) {
        int row = wave * 16 + g4 * 4 + r;
        int col = tt * 16 + r15;
        Psm[row * 64 + (((col >> 3) ^ (row & 7)) << 3) + (col & 7)] =
            (bh)s[tt][r];
      }

    // O += P @ V  (V^T tile rows are output dims -> gemm_bt pattern)
    bh8 pf[2];
#pragma unroll
    for (int kk = 0; kk < 2; ++kk)
      pf[kk] = frag_ld(Psm, wave * 16 + r15, kk * 32 + g4 * 8);
#pragma unroll
    for (int tt = 0; tt < 4; ++tt)
#pragma unroll
      for (int kk = 0; kk < 2; ++kk) {
        bh8 vf = frag_ld(Vtsm, tt * 16 + r15, kk * 32 + g4 * 8);
        acc_o[tt] = mfma16(pf[kk], vf, acc_o[tt]);
      }
    __syncthreads();
  }

  bh* Ob = Op + ((size_t)(b * CS + q0)) * CD + h * 64;
#pragma unroll
  for (int tt = 0; tt < 4; ++tt)
#pragma unroll
    for (int r = 0; r < 4; ++r) {
      int row = wave * 16 + g4 * 4 + r;
      int col = tt * 16 + r15;
      Ob[(size_t)row * CD + col] = (bh)(acc_o[tt][r] / lrow[r]);
    }
}

extern "C" void kernel_launch(void* const* d_in, const int* in_sizes, int n_in,
                              void* d_out, int out_size, void* d_ws,
                              size_t ws_size, hipStream_t stream) {
  const float* query = (const float*)d_in[0];
  const float* key   = (const float*)d_in[1];
  const float* value = (const float*)d_in[2];
  const int*   mask  = (const int*)d_in[3];
  const float* wq = (const float*)d_in[4];
  const float* bq = (const float*)d_in[5];
  const float* wk = (const float*)d_in[6];
  const float* bk = (const float*)d_in[7];
  const float* wv = (const float*)d_in[8];
  const float* bv = (const float*)d_in[9];
  const float* wo = (const float*)d_in[10];
  const float* bo = (const float*)d_in[11];
  float* out = (float*)d_out;

  // ws: Q,K,V projected (bf16) + attention output (bf16) = 4 * 16 MiB = 64 MiB
  const size_t TN = (size_t)CM * CD;
  bh* Qp = (bh*)d_ws;
  bh* Kp = Qp + TN;
  bh* Vp = Kp + TN;
  bh* Ap = Vp + TN;

  const int nwg = (CD / 128) * (CM / 128);  // 8 * 64 = 512 blocks, %8 == 0
  gemm_bt<true, false><<<nwg, 256, 0, stream>>>(query, wq, bq, Qp, CM, CD, CD);
  gemm_bt<true, false><<<nwg, 256, 0, stream>>>(key, wk, bk, Kp, CM, CD, CD);
  gemm_bt<true, false><<<nwg, 256, 0, stream>>>(value, wv, bv, Vp, CM, CD, CD);
  attn_fwd<<<dim3(CS / 64, CB * CH), 256, 0, stream>>>(Qp, Kp, Vp, mask, Ap);
  gemm_bt<false, true><<<nwg, 256, 0, stream>>>(Ap, wo, bo, out, CM, CD, CD);
}

// Round 6
// 565.659 us; speedup vs baseline: 1.2600x; 1.2600x over previous
//
#include <hip/hip_runtime.h>
#include <hip/hip_bf16.h>
#include <stdint.h>

// MHA forward, MI355X/gfx950.
// Pipeline: 4x weight-cast (f32->bf16) + 3x projection GEMM (A f32, B bf16)
//           -> flash attention (bf16) -> output GEMM (bf16 both sides).
// All matmul via v_mfma_f32_16x16x32_bf16, fp32 accumulate.

typedef __bf16 bh;
typedef bh bh8 __attribute__((ext_vector_type(8)));
typedef float f4 __attribute__((ext_vector_type(4)));

#define DEVI static __device__ __forceinline__

constexpr int CB = 4, CS = 2048, CD = 1024, CH = 16;
constexpr int CM = CB * CS;  // 8192 rows

DEVI f4 mfma16(bh8 a, bh8 b, f4 c) {
  return __builtin_amdgcn_mfma_f32_16x16x32_bf16(a, b, c, 0, 0, 0);
}

// async global->LDS, 16B per lane. LDS dest is wave-uniform base + lane*16.
DEVI void gload_lds16(const void* g, void* l) {
  void* gnc = const_cast<void*>(g);
  __builtin_amdgcn_global_load_lds(
      (__attribute__((address_space(1))) void*)gnc,
      (__attribute__((address_space(3))) void*)l, 16, 0, 0);
}

// Fragment read from a [rows][64] bf16 tile, key = row&7 (GEMM/K tiles).
DEVI bh8 frag_ld(const bh* base, int row, int k0) {
  int slot = (k0 >> 3) ^ (row & 7);
  return *(const bh8*)(base + row * 64 + slot * 8);
}

// Fragment read with key = (row&7)^(row>>3) — used for Vt/P tiles whose
// scalar WRITES vary row by 8*(lane&7) (write-side spread needs row>>3).
DEVI bh8 frag_ld2(const bh* base, int row, int k0) {
  int slot = ((k0 >> 3) ^ (row & 7) ^ ((row >> 3) & 7)) & 7;
  return *(const bh8*)(base + row * 64 + slot * 8);
}

DEVI bh8 cvt8(float4 a, float4 b) {
  bh8 v;
  v[0] = (bh)a.x; v[1] = (bh)a.y; v[2] = (bh)a.z; v[3] = (bh)a.w;
  v[4] = (bh)b.x; v[5] = (bh)b.y; v[6] = (bh)b.z; v[7] = (bh)b.w;
  return v;
}

// Elementwise f32 -> bf16 cast (for weights), 8 elems/thread.
__global__ void cast_kern(const float* __restrict__ in, bh* __restrict__ out,
                          int n) {
  int i = (blockIdx.x * 256 + threadIdx.x) * 8;
  if (i < n) {
    const float4* p = (const float4*)(in + i);
    *(bh8*)(out + i) = cvt8(p[0], p[1]);
  }
}

// Stage a 128x64 f32 tile -> swizzled bf16 LDS tile. 256 threads.
DEVI void stage_f32_tile(const float* src, int ld, bh* dst, int t) {
#pragma unroll
  for (int i = 0; i < 4; ++i) {
    int c2 = 2 * t + i * 512;        // float4-chunk index (16 per row), paired
    int row = c2 >> 4;
    int s8 = (c2 & 15) >> 1;         // 16B bf16 slot 0..7
    const float4* sp = (const float4*)(src + (size_t)row * ld) + (c2 & 15);
    float4 a = sp[0], b2 = sp[1];
    int slot = s8 ^ (row & 7);
    *(bh8*)(dst + row * 64 + slot * 8) = cvt8(a, b2);
  }
}

// Stage a 128x64 bf16 tile via global_load_lds: linear LDS dest,
// inverse-swizzled global source (rule #21).
DEVI void stage_bf16_tile(const bh* src, int ld, bh* dst, int wave, int lane) {
#pragma unroll
  for (int i = 0; i < 4; ++i) {
    int c = i * 256 + wave * 64 + lane;
    int row = c >> 3, s8 = c & 7;
    gload_lds16(src + (size_t)row * ld + ((s8 ^ (row & 7)) * 8), dst + c * 8);
  }
}

// C[M,N] = A[M,K] @ B[N,K]^T + bias.  B is bf16 (pre-cast weights).
// 128x128 tile, BK=64, 4 waves (2x2), each wave 64x64 out.
template <bool A_F32, bool OUT_F32>
__global__ __launch_bounds__(256, 2) void gemm_bt(
    const void* __restrict__ Ap, const bh* __restrict__ Bw,
    const float* __restrict__ bias, void* __restrict__ Cp,
    int M, int N, int K) {
  __shared__ __align__(16) bh Asm[128 * 64];
  __shared__ __align__(16) bh Bsm[128 * 64];
  const int t = threadIdx.x;
  const int lane = t & 63, wave = t >> 6;
  const int wm = wave >> 1, wn = wave & 1;

  // XCD-aware chunked swizzle (T1): nwg%8==0 here (512).
  const int ntx = N >> 7, nty = M >> 7;
  const int c = blockIdx.x & 7;                  // XCD slot
  const int l = blockIdx.x >> 3;                 // index within chunk
  const int mt = c * (nty >> 3) + l / ntx;       // M-tile
  const int nt = l % ntx;                        // N-tile
  const int m0 = mt * 128, n0 = nt * 128;
  const int r15 = lane & 15, g4 = lane >> 4;

  const f4 fz = {0.f, 0.f, 0.f, 0.f};
  f4 acc[4][4];
#pragma unroll
  for (int i = 0; i < 4; ++i)
#pragma unroll
    for (int j = 0; j < 4; ++j) acc[i][j] = fz;

  for (int kt = 0; kt < K; kt += 64) {
    if constexpr (A_F32)
      stage_f32_tile((const float*)Ap + (size_t)m0 * K + kt, K, Asm, t);
    else
      stage_bf16_tile((const bh*)Ap + (size_t)m0 * K + kt, K, Asm, wave, lane);
    stage_bf16_tile(Bw + (size_t)n0 * K + kt, K, Bsm, wave, lane);
    __syncthreads();

    bh8 af[4][2], bf_[4][2];
#pragma unroll
    for (int m = 0; m < 4; ++m)
#pragma unroll
      for (int kk = 0; kk < 2; ++kk)
        af[m][kk] = frag_ld(Asm, wm * 64 + m * 16 + r15, kk * 32 + g4 * 8);
#pragma unroll
    for (int n = 0; n < 4; ++n)
#pragma unroll
      for (int kk = 0; kk < 2; ++kk)
        bf_[n][kk] = frag_ld(Bsm, wn * 64 + n * 16 + r15, kk * 32 + g4 * 8);
#pragma unroll
    for (int kk = 0; kk < 2; ++kk)
#pragma unroll
      for (int m = 0; m < 4; ++m)
#pragma unroll
        for (int n = 0; n < 4; ++n)
          acc[m][n] = mfma16(af[m][kk], bf_[n][kk], acc[m][n]);
    __syncthreads();
  }

#pragma unroll
  for (int n = 0; n < 4; ++n) {
    int col = n0 + wn * 64 + n * 16 + r15;
    float bv = bias[col];
#pragma unroll
    for (int m = 0; m < 4; ++m) {
      int row = m0 + wm * 64 + m * 16 + g4 * 4;
#pragma unroll
      for (int r = 0; r < 4; ++r) {
        float v = acc[m][n][r] + bv;
        if constexpr (OUT_F32)
          ((float*)Cp)[(size_t)(row + r) * N + col] = v;
        else
          ((bh*)Cp)[(size_t)(row + r) * N + col] = (bh)v;
      }
    }
  }
}

// Flash attention, one (b,h) x 64 Q-rows per block; 4 waves, 16 rows/wave.
__global__ __launch_bounds__(256, 2) void attn_fwd(
    const bh* __restrict__ Qp, const bh* __restrict__ Kp,
    const bh* __restrict__ Vp, const int* __restrict__ maskp,
    bh* __restrict__ Op) {
  __shared__ __align__(16) bh Ksm[64 * 64];
  __shared__ __align__(16) bh Vtsm[64 * 64];   // V transposed: [d][k]
  __shared__ __align__(16) bh Psm[64 * 64];
  __shared__ float maskadd[64];

  const int t = threadIdx.x;
  const int lane = t & 63, wave = t >> 6;
  const int r15 = lane & 15, g4 = lane >> 4;
  const int b = blockIdx.y >> 4, h = blockIdx.y & 15;
  const int q0 = blockIdx.x * 64;

  const bh* Qb = Qp + ((size_t)(b * CS + q0)) * CD + h * 64;
  const bh* Kb = Kp + ((size_t)b * CS) * CD + h * 64;
  const bh* Vb = Vp + ((size_t)b * CS) * CD + h * 64;
  const int* mb = maskp + b * CS;

  // Q fragments in registers, pre-scaled by 1/sqrt(64)=0.125 (exact in bf16)
  bh8 qf[2];
  {
    int qr = wave * 16 + r15;
#pragma unroll
    for (int kk = 0; kk < 2; ++kk) {
      bh8 v = *(const bh8*)(Qb + (size_t)qr * CD + kk * 32 + g4 * 8);
#pragma unroll
      for (int j = 0; j < 8; ++j) v[j] = (bh)((float)v[j] * 0.125f);
      qf[kk] = v;
    }
  }

  const f4 fz = {0.f, 0.f, 0.f, 0.f};
  f4 acc_o[4];
#pragma unroll
  for (int i = 0; i < 4; ++i) acc_o[i] = fz;
  float mrow[4] = {-1e30f, -1e30f, -1e30f, -1e30f};
  float lrow[4] = {0.f, 0.f, 0.f, 0.f};

  for (int kt = 0; kt < CS; kt += 64) {
    // K tile via global_load_lds, pre-swizzled source (key row&7)
    const bh* Ks = Kb + (size_t)kt * CD;
#pragma unroll
    for (int i = 0; i < 2; ++i) {
      int c = i * 256 + wave * 64 + lane;
      int row = c >> 3, s8 = c & 7;
      gload_lds16(Ks + (size_t)row * CD + ((s8 ^ (row & 7)) * 8), Ksm + c * 8);
    }
    // V tile transposed into LDS. Write key includes (dr>>3)&7 = lane&7 so
    // the 64 lanes of each scalar store spread across all 8 slots (the old
    // (dr&7)-only key was constant per store -> ~8-way bank conflict).
    const bh* Vs = Vb + (size_t)kt * CD;
#pragma unroll
    for (int i = 0; i < 2; ++i) {
      int c = i * 256 + t;
      int k = c >> 3, d0 = (c & 7) * 8;
      bh8 v = *(const bh8*)(Vs + (size_t)k * CD + d0);
#pragma unroll
      for (int j = 0; j < 8; ++j) {
        int dr = d0 + j;
        int slot = ((k >> 3) ^ (dr & 7) ^ ((dr >> 3) & 7)) & 7;
        Vtsm[dr * 64 + slot * 8 + (k & 7)] = v[j];
      }
    }
    if (t < 64) maskadd[t] = (mb[kt + t] == 0) ? -1e9f : 0.0f;
    __syncthreads();

    // S = (Q/8) K^T ; acc layout: row=(g4*4+r) of wave strip, col=key tt*16+r15
    f4 s[4];
#pragma unroll
    for (int tt = 0; tt < 4; ++tt) {
      f4 a = fz;
#pragma unroll
      for (int kk = 0; kk < 2; ++kk) {
        bh8 kf = frag_ld(Ksm, tt * 16 + r15, kk * 32 + g4 * 8);
        a = mfma16(qf[kk], kf, a);
      }
      s[tt] = a;
    }

    // mask + online softmax (wave-parallel: 16-lane butterfly per row group)
    float madd[4];
#pragma unroll
    for (int tt = 0; tt < 4; ++tt) madd[tt] = maskadd[tt * 16 + r15];
    float mx[4];
#pragma unroll
    for (int r = 0; r < 4; ++r) {
      float v0 = s[0][r] + madd[0];
      s[0][r] = v0;
      mx[r] = v0;
    }
#pragma unroll
    for (int tt = 1; tt < 4; ++tt)
#pragma unroll
      for (int r = 0; r < 4; ++r) {
        float v = s[tt][r] + madd[tt];
        s[tt][r] = v;
        mx[r] = fmaxf(mx[r], v);
      }
#pragma unroll
    for (int off = 1; off < 16; off <<= 1)
#pragma unroll
      for (int r = 0; r < 4; ++r) mx[r] = fmaxf(mx[r], __shfl_xor(mx[r], off));

    float corr[4];
#pragma unroll
    for (int r = 0; r < 4; ++r) {
      float mn = fmaxf(mrow[r], mx[r]);
      corr[r] = __expf(mrow[r] - mn);
      mrow[r] = mn;
    }
    float psum[4];
#pragma unroll
    for (int tt = 0; tt < 4; ++tt)
#pragma unroll
      for (int r = 0; r < 4; ++r) {
        float p = __expf(s[tt][r] - mrow[r]);
        s[tt][r] = p;
        psum[r] = (tt == 0) ? p : (psum[r] + p);
      }
#pragma unroll
    for (int off = 1; off < 16; off <<= 1)
#pragma unroll
      for (int r = 0; r < 4; ++r) psum[r] += __shfl_xor(psum[r], off);
#pragma unroll
    for (int r = 0; r < 4; ++r) lrow[r] = lrow[r] * corr[r] + psum[r];
#pragma unroll
    for (int tt = 0; tt < 4; ++tt)
#pragma unroll
      for (int r = 0; r < 4; ++r) acc_o[tt][r] *= corr[r];

    // P -> LDS (bf16). Same extended key so the 16 scalar stores spread.
#pragma unroll
    for (int tt = 0; tt < 4; ++tt)
#pragma unroll
      for (int r = 0; r < 4; ++r) {
        int row = wave * 16 + g4 * 4 + r;
        int col = tt * 16 + r15;
        int slot = ((col >> 3) ^ (row & 7) ^ ((row >> 3) & 7)) & 7;
        Psm[row * 64 + slot * 8 + (col & 7)] = (bh)s[tt][r];
      }

    // O += P @ V  (V^T tile rows are output dims -> gemm_bt pattern)
    bh8 pf[2];
#pragma unroll
    for (int kk = 0; kk < 2; ++kk)
      pf[kk] = frag_ld2(Psm, wave * 16 + r15, kk * 32 + g4 * 8);
#pragma unroll
    for (int tt = 0; tt < 4; ++tt)
#pragma unroll
      for (int kk = 0; kk < 2; ++kk) {
        bh8 vf = frag_ld2(Vtsm, tt * 16 + r15, kk * 32 + g4 * 8);
        acc_o[tt] = mfma16(pf[kk], vf, acc_o[tt]);
      }
    __syncthreads();
  }

  bh* Ob = Op + ((size_t)(b * CS + q0)) * CD + h * 64;
#pragma unroll
  for (int tt = 0; tt < 4; ++tt)
#pragma unroll
    for (int r = 0; r < 4; ++r) {
      int row = wave * 16 + g4 * 4 + r;
      int col = tt * 16 + r15;
      Ob[(size_t)row * CD + col] = (bh)(acc_o[tt][r] / lrow[r]);
    }
}

extern "C" void kernel_launch(void* const* d_in, const int* in_sizes, int n_in,
                              void* d_out, int out_size, void* d_ws,
                              size_t ws_size, hipStream_t stream) {
  const float* query = (const float*)d_in[0];
  const float* key   = (const float*)d_in[1];
  const float* value = (const float*)d_in[2];
  const int*   mask  = (const int*)d_in[3];
  const float* wq = (const float*)d_in[4];
  const float* bq = (const float*)d_in[5];
  const float* wk = (const float*)d_in[6];
  const float* bk = (const float*)d_in[7];
  const float* wv = (const float*)d_in[8];
  const float* bv = (const float*)d_in[9];
  const float* wo = (const float*)d_in[10];
  const float* bo = (const float*)d_in[11];
  float* out = (float*)d_out;

  // ws (64 MiB total):
  //  [ 0,16) Qp        (bf16)  -- dead after attn; wo_bf16 reuses it
  //  [16,32) Kp        (bf16)
  //  [32,48) Vp        (bf16)
  //  [48,64) Ap        (bf16)  -- attn output; wq/wk/wv casts live here
  //                               BEFORE attn writes it (stream-ordered)
  const size_t TN = (size_t)CM * CD;
  bh* Qp = (bh*)d_ws;
  bh* Kp = Qp + TN;
  bh* Vp = Kp + TN;
  bh* Ap = Vp + TN;
  bh* Wearly = Ap;        // weight slot for wq/wk/wv (pre-attention)
  bh* Wlate  = Qp;        // weight slot for wo (Qp dead after attention)

  const int nW = CD * CD;               // 1M elems per weight
  const int castBlocks = nW / (256 * 8);  // 512
  const int nwg = (CD / 128) * (CM / 128);  // 512 blocks, %8 == 0

  cast_kern<<<castBlocks, 256, 0, stream>>>(wq, Wearly, nW);
  gemm_bt<true, false><<<nwg, 256, 0, stream>>>(query, Wearly, bq, Qp, CM, CD, CD);
  cast_kern<<<castBlocks, 256, 0, stream>>>(wk, Wearly, nW);
  gemm_bt<true, false><<<nwg, 256, 0, stream>>>(key, Wearly, bk, Kp, CM, CD, CD);
  cast_kern<<<castBlocks, 256, 0, stream>>>(wv, Wearly, nW);
  gemm_bt<true, false><<<nwg, 256, 0, stream>>>(value, Wearly, bv, Vp, CM, CD, CD);
  attn_fwd<<<dim3(CS / 64, CB * CH), 256, 0, stream>>>(Qp, Kp, Vp, mask, Ap);
  cast_kern<<<castBlocks, 256, 0, stream>>>(wo, Wlate, nW);
  gemm_bt<false, true><<<nwg, 256, 0, stream>>>(Ap, Wlate, bo, out, CM, CD, CD);
}

// Round 7
// 520.285 us; speedup vs baseline: 1.3699x; 1.0872x over previous
//
#include <hip/hip_runtime.h>
#include <hip/hip_bf16.h>
#include <stdint.h>

// MHA forward, MI355X/gfx950.
// Pipeline: cast inputs+weights to bf16 (once) -> 4x bf16 GEMM (m97-structure,
//           gload_lds both sides) -> flash attention (bf16).
// d_out doubles as pre-attention scratch for casted activations/weights.

typedef __bf16 bh;
typedef bh bh8 __attribute__((ext_vector_type(8)));
typedef float f4 __attribute__((ext_vector_type(4)));

#define DEVI static __device__ __forceinline__

constexpr int CB = 4, CS = 2048, CD = 1024, CH = 16;
constexpr int CM = CB * CS;  // 8192 rows

DEVI f4 mfma16(bh8 a, bh8 b, f4 c) {
  return __builtin_amdgcn_mfma_f32_16x16x32_bf16(a, b, c, 0, 0, 0);
}

// async global->LDS, 16B per lane. LDS dest is wave-uniform base + lane*16.
DEVI void gload_lds16(const void* g, void* l) {
  void* gnc = const_cast<void*>(g);
  __builtin_amdgcn_global_load_lds(
      (__attribute__((address_space(1))) void*)gnc,
      (__attribute__((address_space(3))) void*)l, 16, 0, 0);
}

// Fragment read from a [rows][64] bf16 tile, key = row&7 (GEMM/K tiles).
DEVI bh8 frag_ld(const bh* base, int row, int k0) {
  int slot = (k0 >> 3) ^ (row & 7);
  return *(const bh8*)(base + row * 64 + slot * 8);
}

// Fragment read with key = (row&7)^(row>>3) — used for Vt/P tiles whose
// scalar WRITES vary row by 8*(lane&7) (write-side spread needs row>>3).
DEVI bh8 frag_ld2(const bh* base, int row, int k0) {
  int slot = ((k0 >> 3) ^ (row & 7) ^ ((row >> 3) & 7)) & 7;
  return *(const bh8*)(base + row * 64 + slot * 8);
}

DEVI bh8 cvt8(float4 a, float4 b) {
  bh8 v;
  v[0] = (bh)a.x; v[1] = (bh)a.y; v[2] = (bh)a.z; v[3] = (bh)a.w;
  v[4] = (bh)b.x; v[5] = (bh)b.y; v[6] = (bh)b.z; v[7] = (bh)b.w;
  return v;
}

// Elementwise f32 -> bf16 cast, 8 elems/thread.
__global__ void cast_kern(const float* __restrict__ in, bh* __restrict__ out,
                          int n) {
  int i = (blockIdx.x * 256 + threadIdx.x) * 8;
  if (i < n) {
    const float4* p = (const float4*)(in + i);
    *(bh8*)(out + i) = cvt8(p[0], p[1]);
  }
}

// Stage a 128x64 bf16 tile via global_load_lds: linear LDS dest,
// inverse-swizzled global source (rule #21).
DEVI void stage_bf16_tile(const bh* src, int ld, bh* dst, int wave, int lane) {
#pragma unroll
  for (int i = 0; i < 4; ++i) {
    int c = i * 256 + wave * 64 + lane;
    int row = c >> 3, s8 = c & 7;
    gload_lds16(src + (size_t)row * ld + ((s8 ^ (row & 7)) * 8), dst + c * 8);
  }
}

// C[M,N] = A[M,K] @ B[N,K]^T + bias.  All-bf16 inputs (m97 structure).
// 128x128 tile, BK=64, 4 waves (2x2), each wave 64x64 out.
template <bool OUT_F32>
__global__ __launch_bounds__(256, 2) void gemm_bt(
    const bh* __restrict__ Ap, const bh* __restrict__ Bw,
    const float* __restrict__ bias, void* __restrict__ Cp,
    int M, int N, int K) {
  __shared__ __align__(16) bh Asm[128 * 64];
  __shared__ __align__(16) bh Bsm[128 * 64];
  const int t = threadIdx.x;
  const int lane = t & 63, wave = t >> 6;
  const int wm = wave >> 1, wn = wave & 1;

  // XCD-aware chunked swizzle (T1): nwg%8==0 here (512).
  const int ntx = N >> 7, nty = M >> 7;
  const int c = blockIdx.x & 7;                  // XCD slot
  const int l = blockIdx.x >> 3;                 // index within chunk
  const int mt = c * (nty >> 3) + l / ntx;       // M-tile
  const int nt = l % ntx;                        // N-tile
  const int m0 = mt * 128, n0 = nt * 128;
  const int r15 = lane & 15, g4 = lane >> 4;

  const f4 fz = {0.f, 0.f, 0.f, 0.f};
  f4 acc[4][4];
#pragma unroll
  for (int i = 0; i < 4; ++i)
#pragma unroll
    for (int j = 0; j < 4; ++j) acc[i][j] = fz;

  for (int kt = 0; kt < K; kt += 64) {
    stage_bf16_tile(Ap + (size_t)m0 * K + kt, K, Asm, wave, lane);
    stage_bf16_tile(Bw + (size_t)n0 * K + kt, K, Bsm, wave, lane);
    __syncthreads();

    bh8 af[4][2], bf_[4][2];
#pragma unroll
    for (int m = 0; m < 4; ++m)
#pragma unroll
      for (int kk = 0; kk < 2; ++kk)
        af[m][kk] = frag_ld(Asm, wm * 64 + m * 16 + r15, kk * 32 + g4 * 8);
#pragma unroll
    for (int n = 0; n < 4; ++n)
#pragma unroll
      for (int kk = 0; kk < 2; ++kk)
        bf_[n][kk] = frag_ld(Bsm, wn * 64 + n * 16 + r15, kk * 32 + g4 * 8);
#pragma unroll
    for (int kk = 0; kk < 2; ++kk)
#pragma unroll
      for (int m = 0; m < 4; ++m)
#pragma unroll
        for (int n = 0; n < 4; ++n)
          acc[m][n] = mfma16(af[m][kk], bf_[n][kk], acc[m][n]);
    __syncthreads();
  }

#pragma unroll
  for (int n = 0; n < 4; ++n) {
    int col = n0 + wn * 64 + n * 16 + r15;
    float bv = bias[col];
#pragma unroll
    for (int m = 0; m < 4; ++m) {
      int row = m0 + wm * 64 + m * 16 + g4 * 4;
#pragma unroll
      for (int r = 0; r < 4; ++r) {
        float v = acc[m][n][r] + bv;
        if constexpr (OUT_F32)
          ((float*)Cp)[(size_t)(row + r) * N + col] = v;
        else
          ((bh*)Cp)[(size_t)(row + r) * N + col] = (bh)v;
      }
    }
  }
}

// Flash attention, one (b,h) x 64 Q-rows per block; 4 waves, 16 rows/wave.
__global__ __launch_bounds__(256, 2) void attn_fwd(
    const bh* __restrict__ Qp, const bh* __restrict__ Kp,
    const bh* __restrict__ Vp, const int* __restrict__ maskp,
    bh* __restrict__ Op) {
  __shared__ __align__(16) bh Ksm[64 * 64];
  __shared__ __align__(16) bh Vtsm[64 * 64];   // V transposed: [d][k]
  __shared__ __align__(16) bh Psm[64 * 64];
  __shared__ float maskadd[64];

  const int t = threadIdx.x;
  const int lane = t & 63, wave = t >> 6;
  const int r15 = lane & 15, g4 = lane >> 4;
  const int b = blockIdx.y >> 4, h = blockIdx.y & 15;
  const int q0 = blockIdx.x * 64;

  const bh* Qb = Qp + ((size_t)(b * CS + q0)) * CD + h * 64;
  const bh* Kb = Kp + ((size_t)b * CS) * CD + h * 64;
  const bh* Vb = Vp + ((size_t)b * CS) * CD + h * 64;
  const int* mb = maskp + b * CS;

  // Q fragments in registers, pre-scaled by 1/sqrt(64)=0.125 (exact in bf16)
  bh8 qf[2];
  {
    int qr = wave * 16 + r15;
#pragma unroll
    for (int kk = 0; kk < 2; ++kk) {
      bh8 v = *(const bh8*)(Qb + (size_t)qr * CD + kk * 32 + g4 * 8);
#pragma unroll
      for (int j = 0; j < 8; ++j) v[j] = (bh)((float)v[j] * 0.125f);
      qf[kk] = v;
    }
  }

  const f4 fz = {0.f, 0.f, 0.f, 0.f};
  f4 acc_o[4];
#pragma unroll
  for (int i = 0; i < 4; ++i) acc_o[i] = fz;
  float mrow[4] = {-1e30f, -1e30f, -1e30f, -1e30f};
  float lrow[4] = {0.f, 0.f, 0.f, 0.f};

  for (int kt = 0; kt < CS; kt += 64) {
    // K tile via global_load_lds, pre-swizzled source (key row&7)
    const bh* Ks = Kb + (size_t)kt * CD;
#pragma unroll
    for (int i = 0; i < 2; ++i) {
      int c = i * 256 + wave * 64 + lane;
      int row = c >> 3, s8 = c & 7;
      gload_lds16(Ks + (size_t)row * CD + ((s8 ^ (row & 7)) * 8), Ksm + c * 8);
    }
    // V tile transposed into LDS (write key spreads by (dr>>3)&7 = lane&7).
    const bh* Vs = Vb + (size_t)kt * CD;
#pragma unroll
    for (int i = 0; i < 2; ++i) {
      int c = i * 256 + t;
      int k = c >> 3, d0 = (c & 7) * 8;
      bh8 v = *(const bh8*)(Vs + (size_t)k * CD + d0);
#pragma unroll
      for (int j = 0; j < 8; ++j) {
        int dr = d0 + j;
        int slot = ((k >> 3) ^ (dr & 7) ^ ((dr >> 3) & 7)) & 7;
        Vtsm[dr * 64 + slot * 8 + (k & 7)] = v[j];
      }
    }
    if (t < 64) maskadd[t] = (mb[kt + t] == 0) ? -1e9f : 0.0f;
    __syncthreads();

    // S = (Q/8) K^T ; acc layout: row=(g4*4+r) of wave strip, col=key tt*16+r15
    f4 s[4];
#pragma unroll
    for (int tt = 0; tt < 4; ++tt) {
      f4 a = fz;
#pragma unroll
      for (int kk = 0; kk < 2; ++kk) {
        bh8 kf = frag_ld(Ksm, tt * 16 + r15, kk * 32 + g4 * 8);
        a = mfma16(qf[kk], kf, a);
      }
      s[tt] = a;
    }

    // mask + online softmax (wave-parallel: 16-lane butterfly per row group)
    float madd[4];
#pragma unroll
    for (int tt = 0; tt < 4; ++tt) madd[tt] = maskadd[tt * 16 + r15];
    float mx[4];
#pragma unroll
    for (int r = 0; r < 4; ++r) {
      float v0 = s[0][r] + madd[0];
      s[0][r] = v0;
      mx[r] = v0;
    }
#pragma unroll
    for (int tt = 1; tt < 4; ++tt)
#pragma unroll
      for (int r = 0; r < 4; ++r) {
        float v = s[tt][r] + madd[tt];
        s[tt][r] = v;
        mx[r] = fmaxf(mx[r], v);
      }
#pragma unroll
    for (int off = 1; off < 16; off <<= 1)
#pragma unroll
      for (int r = 0; r < 4; ++r) mx[r] = fmaxf(mx[r], __shfl_xor(mx[r], off));

    float corr[4];
#pragma unroll
    for (int r = 0; r < 4; ++r) {
      float mn = fmaxf(mrow[r], mx[r]);
      corr[r] = __expf(mrow[r] - mn);
      mrow[r] = mn;
    }
    float psum[4];
#pragma unroll
    for (int tt = 0; tt < 4; ++tt)
#pragma unroll
      for (int r = 0; r < 4; ++r) {
        float p = __expf(s[tt][r] - mrow[r]);
        s[tt][r] = p;
        psum[r] = (tt == 0) ? p : (psum[r] + p);
      }
#pragma unroll
    for (int off = 1; off < 16; off <<= 1)
#pragma unroll
      for (int r = 0; r < 4; ++r) psum[r] += __shfl_xor(psum[r], off);
#pragma unroll
    for (int r = 0; r < 4; ++r) lrow[r] = lrow[r] * corr[r] + psum[r];
#pragma unroll
    for (int tt = 0; tt < 4; ++tt)
#pragma unroll
      for (int r = 0; r < 4; ++r) acc_o[tt][r] *= corr[r];

    // P -> LDS (bf16). Same extended key so the 16 scalar stores spread.
#pragma unroll
    for (int tt = 0; tt < 4; ++tt)
#pragma unroll
      for (int r = 0; r < 4; ++r) {
        int row = wave * 16 + g4 * 4 + r;
        int col = tt * 16 + r15;
        int slot = ((col >> 3) ^ (row & 7) ^ ((row >> 3) & 7)) & 7;
        Psm[row * 64 + slot * 8 + (col & 7)] = (bh)s[tt][r];
      }

    // O += P @ V  (V^T tile rows are output dims -> gemm_bt pattern)
    bh8 pf[2];
#pragma unroll
    for (int kk = 0; kk < 2; ++kk)
      pf[kk] = frag_ld2(Psm, wave * 16 + r15, kk * 32 + g4 * 8);
#pragma unroll
    for (int tt = 0; tt < 4; ++tt)
#pragma unroll
      for (int kk = 0; kk < 2; ++kk) {
        bh8 vf = frag_ld2(Vtsm, tt * 16 + r15, kk * 32 + g4 * 8);
        acc_o[tt] = mfma16(pf[kk], vf, acc_o[tt]);
      }
    __syncthreads();
  }

  bh* Ob = Op + ((size_t)(b * CS + q0)) * CD + h * 64;
#pragma unroll
  for (int tt = 0; tt < 4; ++tt)
#pragma unroll
    for (int r = 0; r < 4; ++r) {
      int row = wave * 16 + g4 * 4 + r;
      int col = tt * 16 + r15;
      Ob[(size_t)row * CD + col] = (bh)(acc_o[tt][r] / lrow[r]);
    }
}

extern "C" void kernel_launch(void* const* d_in, const int* in_sizes, int n_in,
                              void* d_out, int out_size, void* d_ws,
                              size_t ws_size, hipStream_t stream) {
  const float* query = (const float*)d_in[0];
  const float* key   = (const float*)d_in[1];
  const float* value = (const float*)d_in[2];
  const int*   mask  = (const int*)d_in[3];
  const float* wq = (const float*)d_in[4];
  const float* bq = (const float*)d_in[5];
  const float* wk = (const float*)d_in[6];
  const float* bk = (const float*)d_in[7];
  const float* wv = (const float*)d_in[8];
  const float* bv = (const float*)d_in[9];
  const float* wo = (const float*)d_in[10];
  const float* bo = (const float*)d_in[11];
  float* out = (float*)d_out;

  // ws (64 MiB): Qp | Kp | Vp | Ap  (bf16, 16 MiB each).
  // d_out (32 MiB f32) is free scratch until the final GEMM writes it:
  //   [0,16) MiB: casted activation (Xbf), [16,18) MiB: casted weight (Wbf).
  // wo's cast goes to the Qp region (dead after attention).
  const size_t TN = (size_t)CM * CD;
  bh* Qp = (bh*)d_ws;
  bh* Kp = Qp + TN;
  bh* Vp = Kp + TN;
  bh* Ap = Vp + TN;
  bh* Xbf = (bh*)d_out;          // 16 MiB: casted activation
  bh* Wbf = Xbf + TN;            // 2 MiB: casted weight (pre-attn only)
  bh* Wlate = Qp;                // wo cast target (post-attn)

  const int nW = CD * CD;                   // 1M elems per weight
  const int wB = nW / (256 * 8);            // 512 blocks
  const int nX = CM * CD;                   // 8M elems per activation
  const int xB = nX / (256 * 8);            // 4096 blocks
  const int nwg = (CD / 128) * (CM / 128);  // 512 blocks, %8 == 0

  cast_kern<<<wB, 256, 0, stream>>>(wq, Wbf, nW);
  cast_kern<<<xB, 256, 0, stream>>>(query, Xbf, nX);
  gemm_bt<false><<<nwg, 256, 0, stream>>>(Xbf, Wbf, bq, Qp, CM, CD, CD);
  cast_kern<<<wB, 256, 0, stream>>>(wk, Wbf, nW);
  cast_kern<<<xB, 256, 0, stream>>>(key, Xbf, nX);
  gemm_bt<false><<<nwg, 256, 0, stream>>>(Xbf, Wbf, bk, Kp, CM, CD, CD);
  cast_kern<<<wB, 256, 0, stream>>>(wv, Wbf, nW);
  cast_kern<<<xB, 256, 0, stream>>>(value, Xbf, nX);
  gemm_bt<false><<<nwg, 256, 0, stream>>>(Xbf, Wbf, bv, Vp, CM, CD, CD);
  attn_fwd<<<dim3(CS / 64, CB * CH), 256, 0, stream>>>(Qp, Kp, Vp, mask, Ap);
  cast_kern<<<wB, 256, 0, stream>>>(wo, Wlate, nW);
  gemm_bt<true><<<nwg, 256, 0, stream>>>(Ap, Wlate, bo, out, CM, CD, CD);
}

// Round 9
// 440.200 us; speedup vs baseline: 1.6191x; 1.1819x over previous
//
#include <hip/hip_runtime.h>
#include <hip/hip_bf16.h>
#include <stdint.h>

// MHA forward, MI355X/gfx950.
// Pipeline: cast inputs+weights to bf16 (once) -> 4x bf16 GEMM (m97-structure,
//           gload_lds both sides) -> flash attention (bf16, swapped-QK^T
//           lane-local softmax).
// d_out doubles as pre-attention scratch for casted activations/weights.

typedef __bf16 bh;
typedef bh bh4 __attribute__((ext_vector_type(4)));
typedef bh bh8 __attribute__((ext_vector_type(8)));
typedef float f4 __attribute__((ext_vector_type(4)));
typedef unsigned u32;
typedef u32 u32x2 __attribute__((ext_vector_type(2)));

#define DEVI static __device__ __forceinline__

constexpr int CB = 4, CS = 2048, CD = 1024, CH = 16;
constexpr int CM = CB * CS;  // 8192 rows

DEVI f4 mfma16(bh8 a, bh8 b, f4 c) {
  return __builtin_amdgcn_mfma_f32_16x16x32_bf16(a, b, c, 0, 0, 0);
}

// async global->LDS, 16B per lane. LDS dest is wave-uniform base + lane*16.
DEVI void gload_lds16(const void* g, void* l) {
  void* gnc = const_cast<void*>(g);
  __builtin_amdgcn_global_load_lds(
      (__attribute__((address_space(1))) void*)gnc,
      (__attribute__((address_space(3))) void*)l, 16, 0, 0);
}

// Fragment read from a [rows][64] bf16 tile, key = row&7 (GEMM/K/P tiles).
DEVI bh8 frag_ld(const bh* base, int row, int k0) {
  int slot = (k0 >> 3) ^ (row & 7);
  return *(const bh8*)(base + row * 64 + slot * 8);
}

// Fragment read with key = (row&7)^((row>>3)&7) — V^T tile (write-side spread).
DEVI bh8 frag_ld2(const bh* base, int row, int k0) {
  int slot = ((k0 >> 3) ^ (row & 7) ^ ((row >> 3) & 7)) & 7;
  return *(const bh8*)(base + row * 64 + slot * 8);
}

DEVI u32 pkbb(bh a, bh b) {
  unsigned short ua = __builtin_bit_cast(unsigned short, a);
  unsigned short ub = __builtin_bit_cast(unsigned short, b);
  return (u32)ua | ((u32)ub << 16);
}
DEVI u32 pkff(float a, float b) { return pkbb((bh)a, (bh)b); }

DEVI bh8 cvt8(float4 a, float4 b) {
  bh8 v;
  v[0] = (bh)a.x; v[1] = (bh)a.y; v[2] = (bh)a.z; v[3] = (bh)a.w;
  v[4] = (bh)b.x; v[5] = (bh)b.y; v[6] = (bh)b.z; v[7] = (bh)b.w;
  return v;
}

// Elementwise f32 -> bf16 cast, 8 elems/thread.
__global__ void cast_kern(const float* __restrict__ in, bh* __restrict__ out,
                          int n) {
  int i = (blockIdx.x * 256 + threadIdx.x) * 8;
  if (i < n) {
    const float4* p = (const float4*)(in + i);
    *(bh8*)(out + i) = cvt8(p[0], p[1]);
  }
}

// Stage a 128x64 bf16 tile via global_load_lds: linear LDS dest,
// inverse-swizzled global source (rule #21).
DEVI void stage_bf16_tile(const bh* src, int ld, bh* dst, int wave, int lane) {
#pragma unroll
  for (int i = 0; i < 4; ++i) {
    int c = i * 256 + wave * 64 + lane;
    int row = c >> 3, s8 = c & 7;
    gload_lds16(src + (size_t)row * ld + ((s8 ^ (row & 7)) * 8), dst + c * 8);
  }
}

// C[M,N] = A[M,K] @ B[N,K]^T + bias.  All-bf16 inputs (m97 structure).
template <bool OUT_F32>
__global__ __launch_bounds__(256, 2) void gemm_bt(
    const bh* __restrict__ Ap, const bh* __restrict__ Bw,
    const float* __restrict__ bias, void* __restrict__ Cp,
    int M, int N, int K) {
  __shared__ __align__(16) bh Asm[128 * 64];
  __shared__ __align__(16) bh Bsm[128 * 64];
  const int t = threadIdx.x;
  const int lane = t & 63, wave = t >> 6;
  const int wm = wave >> 1, wn = wave & 1;

  const int ntx = N >> 7, nty = M >> 7;
  const int c = blockIdx.x & 7;
  const int l = blockIdx.x >> 3;
  const int mt = c * (nty >> 3) + l / ntx;
  const int nt = l % ntx;
  const int m0 = mt * 128, n0 = nt * 128;
  const int r15 = lane & 15, g4 = lane >> 4;

  const f4 fz = {0.f, 0.f, 0.f, 0.f};
  f4 acc[4][4];
#pragma unroll
  for (int i = 0; i < 4; ++i)
#pragma unroll
    for (int j = 0; j < 4; ++j) acc[i][j] = fz;

  for (int kt = 0; kt < K; kt += 64) {
    stage_bf16_tile(Ap + (size_t)m0 * K + kt, K, Asm, wave, lane);
    stage_bf16_tile(Bw + (size_t)n0 * K + kt, K, Bsm, wave, lane);
    __syncthreads();

    bh8 af[4][2], bf_[4][2];
#pragma unroll
    for (int m = 0; m < 4; ++m)
#pragma unroll
      for (int kk = 0; kk < 2; ++kk)
        af[m][kk] = frag_ld(Asm, wm * 64 + m * 16 + r15, kk * 32 + g4 * 8);
#pragma unroll
    for (int n = 0; n < 4; ++n)
#pragma unroll
      for (int kk = 0; kk < 2; ++kk)
        bf_[n][kk] = frag_ld(Bsm, wn * 64 + n * 16 + r15, kk * 32 + g4 * 8);
#pragma unroll
    for (int kk = 0; kk < 2; ++kk)
#pragma unroll
      for (int m = 0; m < 4; ++m)
#pragma unroll
        for (int n = 0; n < 4; ++n)
          acc[m][n] = mfma16(af[m][kk], bf_[n][kk], acc[m][n]);
    __syncthreads();
  }

#pragma unroll
  for (int n = 0; n < 4; ++n) {
    int col = n0 + wn * 64 + n * 16 + r15;
    float bv = bias[col];
#pragma unroll
    for (int m = 0; m < 4; ++m) {
      int row = m0 + wm * 64 + m * 16 + g4 * 4;
#pragma unroll
      for (int r = 0; r < 4; ++r) {
        float v = acc[m][n][r] + bv;
        if constexpr (OUT_F32)
          ((float*)Cp)[(size_t)(row + r) * N + col] = v;
        else
          ((bh*)Cp)[(size_t)(row + r) * N + col] = (bh)v;
      }
    }
  }
}

// Flash attention, swapped-QK^T: S^T = mfma(K,Q) puts q=lane&15 lane-local.
// One (b,h) x 64 Q-rows per block; 4 waves, 16 q-rows/wave.
__global__ __launch_bounds__(256, 2) void attn_fwd(
    const bh* __restrict__ Qp, const bh* __restrict__ Kp,
    const bh* __restrict__ Vp, const int* __restrict__ maskp,
    bh* __restrict__ Op) {
  __shared__ __align__(16) bh Ksm[64 * 64];
  __shared__ __align__(16) bh Vtsm[64 * 64];   // V transposed: [d][k]
  __shared__ __align__(16) bh Psm[64 * 64];    // P: [q][k]

  const int t = threadIdx.x;
  const int lane = t & 63, wave = t >> 6;
  const int r15 = lane & 15, g4 = lane >> 4;
  const int b = blockIdx.y >> 4, h = blockIdx.y & 15;
  const int q0 = blockIdx.x * 64;

  const bh* Qb = Qp + ((size_t)(b * CS + q0)) * CD + h * 64;
  const bh* Kb = Kp + ((size_t)b * CS) * CD + h * 64;
  const bh* Vb = Vp + ((size_t)b * CS) * CD + h * 64;
  const int* mb = maskp + b * CS;

  // Q fragments (MFMA B-operand, rows=q), pre-scaled by 1/8 (exact in bf16)
  bh8 qf[2];
  {
    int qr = wave * 16 + r15;
#pragma unroll
    for (int kk = 0; kk < 2; ++kk) {
      bh8 v = *(const bh8*)(Qb + (size_t)qr * CD + kk * 32 + g4 * 8);
#pragma unroll
      for (int j = 0; j < 8; ++j) v[j] = (bh)((float)v[j] * 0.125f);
      qf[kk] = v;
    }
  }

  const f4 fz = {0.f, 0.f, 0.f, 0.f};
  f4 acc_o[4];
#pragma unroll
  for (int i = 0; i < 4; ++i) acc_o[i] = fz;
  float mrow = -1e30f, lrow = 0.f;  // per-lane scalars for q = r15

  // V staging geometry: thread t covers k=[vk0,vk0+4), d=[vd0,vd0+4)
  const int vk0 = (t >> 4) * 4;
  const int vd0 = (t & 15) * 4;

  for (int kt = 0; kt < CS; kt += 64) {
    // K tile via global_load_lds, pre-swizzled source (key row&7)
    const bh* Ks = Kb + (size_t)kt * CD;
#pragma unroll
    for (int i = 0; i < 2; ++i) {
      int c = i * 256 + wave * 64 + lane;
      int row = c >> 3, s8 = c & 7;
      gload_lds16(Ks + (size_t)row * CD + ((s8 ^ (row & 7)) * 8), Ksm + c * 8);
    }
    // V tile -> V^T in LDS: 4x b64 global, pack pairs along k, 4x b64 writes.
    {
      const bh* Vs = Vb + (size_t)kt * CD;
      bh4 vl[4];
#pragma unroll
      for (int i = 0; i < 4; ++i)
        vl[i] = *(const bh4*)(Vs + (size_t)(vk0 + i) * CD + vd0);
#pragma unroll
      for (int i = 0; i < 4; ++i) {
        int d = vd0 + i;
        u32x2 w2;
        w2[0] = pkbb(vl[0][i], vl[1][i]);
        w2[1] = pkbb(vl[2][i], vl[3][i]);
        int slot = ((vk0 >> 3) ^ (d & 7) ^ ((d >> 3) & 7)) & 7;
        *(u32x2*)(Vtsm + d * 64 + slot * 8 + (vk0 & 7)) = w2;
      }
    }
    __syncthreads();

    // S^T = K (Q/8)^T : lane holds q=r15, keys tt*16+g4*4+r
    f4 s[4];
#pragma unroll
    for (int tt = 0; tt < 4; ++tt) {
      f4 a = fz;
#pragma unroll
      for (int kk = 0; kk < 2; ++kk) {
        bh8 kf = frag_ld(Ksm, tt * 16 + r15, kk * 32 + g4 * 8);
        a = mfma16(kf, qf[kk], a);
      }
      s[tt] = a;
    }

    // mask (additive -1e9), direct from global (L2-resident)
#pragma unroll
    for (int tt = 0; tt < 4; ++tt) {
      int4 mv = *(const int4*)(mb + kt + tt * 16 + 4 * g4);
      s[tt][0] += (mv.x == 0) ? -1e9f : 0.0f;
      s[tt][1] += (mv.y == 0) ? -1e9f : 0.0f;
      s[tt][2] += (mv.z == 0) ? -1e9f : 0.0f;
      s[tt][3] += (mv.w == 0) ? -1e9f : 0.0f;
    }

    // online softmax: in-lane reduce over 16, cross-lane over g4 (2 shfl/pass)
    float pm = s[0][0];
#pragma unroll
    for (int tt = 0; tt < 4; ++tt)
#pragma unroll
      for (int r = 0; r < 4; ++r) pm = fmaxf(pm, s[tt][r]);
    pm = fmaxf(pm, __shfl_xor(pm, 16));
    pm = fmaxf(pm, __shfl_xor(pm, 32));

    float mn = fmaxf(mrow, pm);
    float corr = __expf(mrow - mn);
    mrow = mn;
    float psum = 0.f;
#pragma unroll
    for (int tt = 0; tt < 4; ++tt)
#pragma unroll
      for (int r = 0; r < 4; ++r) {
        float p = __expf(s[tt][r] - mn);
        s[tt][r] = p;
        psum += p;
      }
    psum += __shfl_xor(psum, 16);
    psum += __shfl_xor(psum, 32);
    lrow = lrow * corr + psum;

    // redistribute corr to PV-accumulator lanes (q_out = g4*4+r)
    float co[4];
#pragma unroll
    for (int r = 0; r < 4; ++r) co[r] = __shfl(corr, 4 * g4 + r);
#pragma unroll
    for (int tt = 0; tt < 4; ++tt)
#pragma unroll
      for (int r = 0; r < 4; ++r) acc_o[tt][r] *= co[r];

    // P -> LDS [q][key], bf16-packed, 4x b64 writes (keys consecutive in regs)
    {
      int q = wave * 16 + r15;
#pragma unroll
      for (int tt = 0; tt < 4; ++tt) {
        int key0 = tt * 16 + 4 * g4;
        u32x2 w2;
        w2[0] = pkff(s[tt][0], s[tt][1]);
        w2[1] = pkff(s[tt][2], s[tt][3]);
        int slot = ((key0 >> 3) ^ (q & 7)) & 7;
        *(u32x2*)(Psm + q * 64 + slot * 8 + (key0 & 7)) = w2;
      }
    }

    // O += P @ V  (wave-private P rows; same-wave LDS ordering)
    bh8 pf[2];
#pragma unroll
    for (int kk = 0; kk < 2; ++kk)
      pf[kk] = frag_ld(Psm, wave * 16 + r15, kk * 32 + g4 * 8);
#pragma unroll
    for (int tt = 0; tt < 4; ++tt)
#pragma unroll
      for (int kk = 0; kk < 2; ++kk) {
        bh8 vf = frag_ld2(Vtsm, tt * 16 + r15, kk * 32 + g4 * 8);
        acc_o[tt] = mfma16(pf[kk], vf, acc_o[tt]);
      }
    __syncthreads();
  }

  // epilogue: fetch lrow for q_out rows, divide, store
  float lo[4];
#pragma unroll
  for (int r = 0; r < 4; ++r) lo[r] = __shfl(lrow, 4 * g4 + r);
  bh* Ob = Op + ((size_t)(b * CS + q0)) * CD + h * 64;
#pragma unroll
  for (int tt = 0; tt < 4; ++tt)
#pragma unroll
    for (int r = 0; r < 4; ++r) {
      int row = wave * 16 + g4 * 4 + r;
      int col = tt * 16 + r15;
      Ob[(size_t)row * CD + col] = (bh)(acc_o[tt][r] / lo[r]);
    }
}

extern "C" void kernel_launch(void* const* d_in, const int* in_sizes, int n_in,
                              void* d_out, int out_size, void* d_ws,
                              size_t ws_size, hipStream_t stream) {
  const float* query = (const float*)d_in[0];
  const float* key   = (const float*)d_in[1];
  const float* value = (const float*)d_in[2];
  const int*   mask  = (const int*)d_in[3];
  const float* wq = (const float*)d_in[4];
  const float* bq = (const float*)d_in[5];
  const float* wk = (const float*)d_in[6];
  const float* bk = (const float*)d_in[7];
  const float* wv = (const float*)d_in[8];
  const float* bv = (const float*)d_in[9];
  const float* wo = (const float*)d_in[10];
  const float* bo = (const float*)d_in[11];
  float* out = (float*)d_out;

  const size_t TN = (size_t)CM * CD;
  bh* Qp = (bh*)d_ws;
  bh* Kp = Qp + TN;
  bh* Vp = Kp + TN;
  bh* Ap = Vp + TN;
  bh* Xbf = (bh*)d_out;          // 16 MiB: casted activation (pre-attn scratch)
  bh* Wbf = Xbf + TN;            // 2 MiB: casted weight (pre-attn scratch)
  bh* Wlate = Qp;                // wo cast target (Qp dead after attention)

  const int nW = CD * CD;
  const int wB = nW / (256 * 8);
  const int nX = CM * CD;
  const int xB = nX / (256 * 8);
  const int nwg = (CD / 128) * (CM / 128);  // 512 blocks, %8 == 0

  cast_kern<<<wB, 256, 0, stream>>>(wq, Wbf, nW);
  cast_kern<<<xB, 256, 0, stream>>>(query, Xbf, nX);
  gemm_bt<false><<<nwg, 256, 0, stream>>>(Xbf, Wbf, bq, Qp, CM, CD, CD);
  cast_kern<<<wB, 256, 0, stream>>>(wk, Wbf, nW);
  cast_kern<<<xB, 256, 0, stream>>>(key, Xbf, nX);
  gemm_bt<false><<<nwg, 256, 0, stream>>>(Xbf, Wbf, bk, Kp, CM, CD, CD);
  cast_kern<<<wB, 256, 0, stream>>>(wv, Wbf, nW);
  cast_kern<<<xB, 256, 0, stream>>>(value, Xbf, nX);
  gemm_bt<false><<<nwg, 256, 0, stream>>>(Xbf, Wbf, bv, Vp, CM, CD, CD);
  attn_fwd<<<dim3(CS / 64, CB * CH), 256, 0, stream>>>(Qp, Kp, Vp, mask, Ap);
  cast_kern<<<wB, 256, 0, stream>>>(wo, Wlate, nW);
  gemm_bt<true><<<nwg, 256, 0, stream>>>(Ap, Wlate, bo, out, CM, CD, CD);
}